// Round 1
// baseline (43.145 us; speedup 1.0000x reference)
//
#include <hip/hip_runtime.h>
#include <math.h>

// BatchAllTripletLoss, reduced form.
// batch = concat(h1,h2) : (512, 256) f32.
// dists[i,j] = max(sq[i]+sq[j]-2*dot(b_i,b_j), 1e-7)
// mask nonzero only at k = j ^ pair (j+256 mod 512):
//   t(i,j) = relu(dists[i,j] - dists[i,pair(j)] + 1)
// outputs (5 x f32): loss, mean(differences)=0, good, bad, sqrt(mean(sq))

#define NN 512
#define D  256
#define D4 64   // D/4

__device__ __forceinline__ const float* batch_row(const float* __restrict__ h1,
                                                  const float* __restrict__ h2,
                                                  int r) {
    return (r < 256) ? (h1 + (size_t)r * D) : (h2 + (size_t)(r - 256) * D);
}

// --- K1: squared norms of all 512 rows -----------------------------------
__global__ __launch_bounds__(64) void sq_kernel(const float* __restrict__ h1,
                                                const float* __restrict__ h2,
                                                float* __restrict__ sq) {
    int r = blockIdx.x;          // 0..511
    int lane = threadIdx.x;      // 0..63
    const float4* row = reinterpret_cast<const float4*>(batch_row(h1, h2, r));
    float4 v = row[lane];        // 64 lanes x 16B = 256 floats
    float s = v.x * v.x + v.y * v.y + v.z * v.z + v.w * v.w;
#pragma unroll
    for (int off = 32; off > 0; off >>= 1) s += __shfl_down(s, off);
    if (lane == 0) sq[r] = s;
}

// --- K2: one block per row i; full dists row in LDS; pair stats ----------
__global__ __launch_bounds__(256) void row_stats_kernel(const float* __restrict__ h1,
                                                        const float* __restrict__ h2,
                                                        const float* __restrict__ sq,
                                                        float* __restrict__ partials) {
    int i = blockIdx.x;          // row 0..511
    int t = threadIdx.x;         // 0..255
    __shared__ float4 arow[D4];  // row i staged (broadcast reads)
    __shared__ float  drow[NN];  // dists row i
    __shared__ float  red[3][4];

    if (t < D4) arow[t] = reinterpret_cast<const float4*>(batch_row(h1, h2, i))[t];
    __syncthreads();

    float sqi = sq[i];
#pragma unroll
    for (int half = 0; half < 2; ++half) {
        int j = t + half * 256;
        const float4* rj = reinterpret_cast<const float4*>(batch_row(h1, h2, j));
        float acc = 0.f;
#pragma unroll 16
        for (int k = 0; k < D4; ++k) {
            float4 b = rj[k];
            float4 a = arow[k];
            acc = fmaf(a.x, b.x, acc);
            acc = fmaf(a.y, b.y, acc);
            acc = fmaf(a.z, b.z, acc);
            acc = fmaf(a.w, b.w, acc);
        }
        float dist = sqi + sq[j] - 2.f * acc;
        drow[j] = fmaxf(dist, 1e-7f);   // max(max(x,0),1e-7) == max(x,1e-7)
    }
    __syncthreads();

    // thread t owns the (j=t, k=t+256) and (j=t+256, k=t) masked entries
    float d1 = drow[t];
    float d2 = drow[t + 256];
    float t1 = fmaxf(d1 - d2 + 1.0f, 0.f);
    float t2 = fmaxf(d2 - d1 + 1.0f, 0.f);
    float srel = (t1 > 1e-5f ? t1 : 0.f) + (t2 > 1e-5f ? t2 : 0.f);
    float crel = (float)((t1 > 1e-5f) + (t2 > 1e-5f));
    float good = (float)((t1 < 1e-5f) + (t2 < 1e-5f));

#pragma unroll
    for (int off = 32; off > 0; off >>= 1) {
        srel += __shfl_down(srel, off);
        crel += __shfl_down(crel, off);
        good += __shfl_down(good, off);
    }
    int wave = t >> 6;
    if ((t & 63) == 0) { red[0][wave] = srel; red[1][wave] = crel; red[2][wave] = good; }
    __syncthreads();
    if (t == 0) {
        partials[i * 3 + 0] = red[0][0] + red[0][1] + red[0][2] + red[0][3];
        partials[i * 3 + 1] = red[1][0] + red[1][1] + red[1][2] + red[1][3];
        partials[i * 3 + 2] = red[2][0] + red[2][1] + red[2][2] + red[2][3];
    }
}

// --- K3: final reduction + all 5 outputs ----------------------------------
__global__ __launch_bounds__(512) void finalize_kernel(const float* __restrict__ sq,
                                                       const float* __restrict__ partials,
                                                       float* __restrict__ out) {
    int t = threadIdx.x;   // 0..511
    float s = partials[t * 3 + 0];
    float c = partials[t * 3 + 1];
    float g = partials[t * 3 + 2];
    float q = sq[t];
#pragma unroll
    for (int off = 32; off > 0; off >>= 1) {
        s += __shfl_down(s, off);
        c += __shfl_down(c, off);
        g += __shfl_down(g, off);
        q += __shfl_down(q, off);
    }
    __shared__ float red[4][8];
    int wave = t >> 6;
    if ((t & 63) == 0) { red[0][wave] = s; red[1][wave] = c; red[2][wave] = g; red[3][wave] = q; }
    __syncthreads();
    if (t == 0) {
        float ss = 0.f, cc = 0.f, gg = 0.f, qq = 0.f;
#pragma unroll
        for (int w = 0; w < 8; ++w) { ss += red[0][w]; cc += red[1][w]; gg += red[2][w]; qq += red[3][w]; }
        float mean_sq  = qq / 512.0f;
        float mean_rel = ss / cc;
        float goodTot  = 133955584.0f + gg;      // (512^3 - 512^2) + good_masked
        out[0] = mean_rel + 1e-4f * mean_sq;     // loss
        out[1] = 0.0f;                           // mean(differences) == 0 exactly
        out[2] = goodTot;                        // good
        out[3] = 134217728.0f - goodTot;         // bad = 512^3 - good
        out[4] = sqrtf(mean_sq);                 // sqrt(mean norm^2)
    }
}

extern "C" void kernel_launch(void* const* d_in, const int* in_sizes, int n_in,
                              void* d_out, int out_size, void* d_ws, size_t ws_size,
                              hipStream_t stream) {
    (void)in_sizes; (void)n_in; (void)out_size; (void)ws_size;
    const float* h1 = (const float*)d_in[0];
    const float* h2 = (const float*)d_in[1];
    // d_in[2] (h3) is unused by the reference forward.
    float* ws       = (float*)d_ws;
    float* sq       = ws;          // 512 floats
    float* partials = ws + 512;    // 3*512 floats
    float* out      = (float*)d_out;

    sq_kernel<<<512, 64, 0, stream>>>(h1, h2, sq);
    row_stats_kernel<<<512, 256, 0, stream>>>(h1, h2, sq, partials);
    finalize_kernel<<<1, 512, 0, stream>>>(sq, partials, out);
}